// Round 2
// baseline (87.412 us; speedup 1.0000x reference)
//
#include <hip/hip_runtime.h>
#include <hip/hip_bf16.h>

#define F_DIM 512
#define NT 512
#define DEPTH 5
#define NCOL (NT * DEPTH)   // 2560
#define BATCH 2048

typedef __attribute__((ext_vector_type(8))) short bf16x8;
typedef __attribute__((ext_vector_type(4))) float f32x4;

__device__ __forceinline__ void gl2lds16(const void* g, void* l) {
    __builtin_amdgcn_global_load_lds((const __attribute__((address_space(1))) void*)g,
                                     (__attribute__((address_space(3))) void*)l,
                                     16, 0, 0);
}

__device__ __forceinline__ bf16x8 pack8(float4 a, float4 b) {
    union { bf16x8 v; __hip_bfloat16 h[8]; } u;
    u.h[0] = __float2bfloat16(a.x); u.h[1] = __float2bfloat16(a.y);
    u.h[2] = __float2bfloat16(a.z); u.h[3] = __float2bfloat16(a.w);
    u.h[4] = __float2bfloat16(b.x); u.h[5] = __float2bfloat16(b.y);
    u.h[6] = __float2bfloat16(b.z); u.h[7] = __float2bfloat16(b.w);
    return u.v;
}

// ---------------------------------------------------------------------------
// Kernel 1: prep = column-softmax only (x-cast eliminated; GEMM stages A
// straight from f32 x). 80 blocks x 512 threads. Reduction order identical
// to prior rounds (16 groups x 32 sequential rows) => bit-identical Wt.
// ---------------------------------------------------------------------------
__global__ __launch_bounds__(512) void prep(const float* __restrict__ fa,
                                            __hip_bfloat16* __restrict__ Wt) {
    const int l = threadIdx.x & 31;
    const int g = threadIdx.x >> 5;          // 0..15
    const int col = blockIdx.x * 32 + l;
    const int f0 = g * 32;
    __shared__ float red[16][32];

    float e[32];
    float s = 0.f;
#pragma unroll
    for (int i = 0; i < 32; ++i) {
        e[i] = __expf(fa[(size_t)(f0 + i) * NCOL + col]);
        s += e[i];
    }
    red[g][l] = s;
    __syncthreads();

    float S = 0.f;
#pragma unroll
    for (int gg = 0; gg < 16; ++gg) S += red[gg][l];
    const float inv = 1.0f / S;

    __hip_bfloat16* dst = Wt + (size_t)col * F_DIM + f0;
#pragma unroll
    for (int i = 0; i < 32; i += 8) {
        union { uint4 u; __hip_bfloat16 h[8]; } pk;
#pragma unroll
        for (int jj = 0; jj < 8; ++jj)
            pk.h[jj] = __float2bfloat16(e[i + jj] * inv);
        *(uint4*)(dst + i) = pk.u;
    }
}

// ---------------------------------------------------------------------------
// Kernel 2: fused GEMM + tree routing, v6.
// A is reg-staged from f32 x (cast in-reg, bit-identical to old prep cast):
//   iter kt: issue A-loads(kt+1) [oldest], B gl2lds(kt+1); vmcnt(9) drains
//   B(kt) only; barrier; compute buf cur; vmcnt(5) frees A regs (B(kt+1)
//   stays in flight across the barrier); ds_write A(kt+1); lgkm(0); barrier.
// Inner MFMA loop and epilogue unchanged from v5.
// ---------------------------------------------------------------------------
__global__ __launch_bounds__(256, 2) void gemm_tree(const float* __restrict__ x,
                                                    const __hip_bfloat16* __restrict__ Bt,
                                                    const float* __restrict__ th,
                                                    const float* __restrict__ lt,
                                                    const float* __restrict__ resp,
                                                    float* __restrict__ out) {
    __shared__ __align__(16) char smem[57344];   // 2 x (As 8KB + Bs 20KB); E slab reuses buf0

    const int tid = threadIdx.x;
    const int w = tid >> 6;
    const int l = tid & 63;
    const int m0 = blockIdx.y * 64;       // batch-row base
    const int n0c = blockIdx.x * 160;     // fv-column base
    const int n0t = blockIdx.x * 32;      // tree base
    const int wm = (w & 1) * 32;
    const int wn = (w >> 1) * 80;

    f32x4 acc[2][5] = {};

    const int srow = l >> 3;              // row within 8-row staging group (B)
    const int schunk = (l & 7) ^ srow;    // xor-swizzled source chunk (B)

    const int ar = tid >> 2;              // A staging: row 0..63 (4 thr/row)
    const int ac = (tid & 3) * 2;         // A chunk base 0,2,4,6 (8 bf16/chunk)

    float4 av0, av1, av2, av3;            // A(kt+1) in-flight registers

    auto a_load = [&](int kt) {
        const float* p = x + (size_t)(m0 + ar) * F_DIM + kt * 64 + ac * 8;
        av0 = ((const float4*)p)[0];
        av1 = ((const float4*)p)[1];
        av2 = ((const float4*)p)[2];
        av3 = ((const float4*)p)[3];
    };
    auto a_write = [&](int buf) {
        __hip_bfloat16* As = (__hip_bfloat16*)(smem + buf * 28672);
        *(bf16x8*)(As + ar * 64 + ((ac ^ (ar & 7)) * 8))       = pack8(av0, av1);
        *(bf16x8*)(As + ar * 64 + (((ac + 1) ^ (ar & 7)) * 8)) = pack8(av2, av3);
    };
    auto stageB = [&](int kt, int buf) {
        const int k0 = kt * 64;
        char* base = smem + buf * 28672 + 8192;
#pragma unroll
        for (int q = 0; q < 5; ++q) {     // Bs: 20 groups of 8 rows
            const int g = q * 4 + w;
            gl2lds16(Bt + ((size_t)(n0c + g * 8 + srow) * F_DIM + k0 + schunk * 8),
                     base + g * 8 * 64 * 2);
        }
    };
    auto compute = [&](int cur) {
        const __hip_bfloat16* As = (const __hip_bfloat16*)(smem + cur * 28672);
        const __hip_bfloat16* Bs = As + 4096;   // +8192 bytes
#pragma unroll
        for (int ks = 0; ks < 2; ++ks) {
            const int cb = ks * 4 + (l >> 4);
            bf16x8 af[2], bfr[5];
#pragma unroll
            for (int im = 0; im < 2; ++im) {
                const int r = wm + im * 16 + (l & 15);
                af[im] = *(const bf16x8*)(As + r * 64 + ((cb ^ (r & 7)) * 8));
            }
#pragma unroll
            for (int in = 0; in < 5; ++in) {
                const int r = wn + in * 16 + (l & 15);
                bfr[in] = *(const bf16x8*)(Bs + r * 64 + ((cb ^ (r & 7)) * 8));
            }
#pragma unroll
            for (int im = 0; im < 2; ++im)
#pragma unroll
                for (int in = 0; in < 5; ++in)
                    acc[im][in] = __builtin_amdgcn_mfma_f32_16x16x32_bf16(
                        af[im], bfr[in], acc[im][in], 0, 0, 0);
        }
    };

    // ---- prologue: A(0) regs + B(0) gl2lds; write A(0) while B(0) flies ----
    a_load(0);                                             // 4 vmem (oldest)
    __builtin_amdgcn_sched_barrier(0);
    stageB(0, 0);                                          // 5 vmem
    __builtin_amdgcn_sched_barrier(0);
    asm volatile("s_waitcnt vmcnt(5)" ::: "memory");       // A(0) regs ready
    a_write(0);
    asm volatile("s_waitcnt lgkmcnt(0)" ::: "memory");
    __builtin_amdgcn_sched_barrier(0);

#pragma unroll
    for (int kt = 0; kt < 8; ++kt) {
        const int cur = kt & 1;
        if (kt < 7) {
            a_load(kt + 1);                                // 4 vmem
            __builtin_amdgcn_sched_barrier(0);
            stageB(kt + 1, cur ^ 1);                       // 5 vmem
            __builtin_amdgcn_sched_barrier(0);
            asm volatile("s_waitcnt vmcnt(9)" ::: "memory");   // B(kt) landed
        } else {
            asm volatile("s_waitcnt vmcnt(0)" ::: "memory");
        }
        __builtin_amdgcn_s_barrier();
        __builtin_amdgcn_sched_barrier(0);

        compute(cur);
        __builtin_amdgcn_sched_barrier(0);

        if (kt < 7) {
            asm volatile("s_waitcnt vmcnt(5)" ::: "memory");   // A(kt+1) regs ready
            a_write(cur ^ 1);
            asm volatile("s_waitcnt lgkmcnt(0)" ::: "memory");
            __builtin_amdgcn_sched_barrier(0);
            __builtin_amdgcn_s_barrier();
        }
    }
    __builtin_amdgcn_sched_barrier(0);

    // ---- tree epilogue (unchanged) ----
    float* E = (float*)smem;              // [32][161], reuses buf0
    const int tree = tid & 31;            // local tree 0..31
    const int rg = tid >> 5;              // row-group 0..7 (4 slab rows each)
    const int gt = n0t + tree;

    float al[DEPTH], be[DEPTH];
#pragma unroll
    for (int j = 0; j < DEPTH; ++j) {
        const float a = 0.5f * __expf(-lt[gt * DEPTH + j]);
        al[j] = a;
        be[j] = 0.5f - th[gt * DEPTH + j] * a;
    }
    float rs[32];
#pragma unroll
    for (int i = 0; i < 32; ++i) rs[i] = resp[gt * 32 + i];

    const int PAD = 161;
#pragma unroll
    for (int im = 0; im < 2; ++im) {
#pragma unroll
        for (int in = 0; in < 5; ++in) {
            const int scol = wn + in * 16 + (l & 15);
#pragma unroll
            for (int r = 0; r < 4; ++r) {
                const int sr = (w & 1) * 16 + (l >> 4) * 4 + r;
                E[sr * PAD + scol] = acc[im][in][r];
            }
        }
        __syncthreads();

#pragma unroll
        for (int rr = 0; rr < 4; ++rr) {
            const int s = rg * 4 + rr;                       // slab row 0..31
            const int gb = m0 + ((s < 16) ? (im * 16 + s) : (32 + im * 16 + (s - 16)));
            const float* f = E + s * PAD + tree * 5;
            float c1[DEPTH];
#pragma unroll
            for (int j = 0; j < DEPTH; ++j) {
                const float v = fmaf(al[j], f[j], be[j]);
                c1[j] = fminf(fmaxf(v, 0.f), 1.f);
            }
            float s16[16], s8[8], s4[4], s2[2];
#pragma unroll
            for (int m = 0; m < 16; ++m) s16[m] = fmaf(c1[0], rs[2*m+1] - rs[2*m], rs[2*m]);
#pragma unroll
            for (int m = 0; m < 8; ++m)  s8[m]  = fmaf(c1[1], s16[2*m+1] - s16[2*m], s16[2*m]);
#pragma unroll
            for (int m = 0; m < 4; ++m)  s4[m]  = fmaf(c1[2], s8[2*m+1] - s8[2*m], s8[2*m]);
#pragma unroll
            for (int m = 0; m < 2; ++m)  s2[m]  = fmaf(c1[3], s4[2*m+1] - s4[2*m], s4[2*m]);
            out[(size_t)gb * NT + gt] = fmaf(c1[4], s2[1] - s2[0], s2[0]);
        }
        __syncthreads();
    }
}

// ---------------------------------------------------------------------------
extern "C" void kernel_launch(void* const* d_in, const int* in_sizes, int n_in,
                              void* d_out, int out_size, void* d_ws, size_t ws_size,
                              hipStream_t stream) {
    const float* x    = (const float*)d_in[0];
    const float* fa   = (const float*)d_in[1];
    const float* th   = (const float*)d_in[2];
    const float* lt   = (const float*)d_in[3];
    const float* resp = (const float*)d_in[4];
    // d_in[5] = path_map: deterministic oblivious layout, hardcoded in epilogue.

    char* ws = (char*)d_ws;
    __hip_bfloat16* Wt = (__hip_bfloat16*)(ws);                 // 2560*512*2 = 2.62 MB
    float* out = (float*)d_out;

    hipLaunchKernelGGL(prep, dim3(80), dim3(512), 0, stream, fa, Wt);
    hipLaunchKernelGGL(gemm_tree, dim3(NCOL / 160, BATCH / 64), dim3(256), 0, stream,
                       x, Wt, th, lt, resp, out);
}

// Round 3
// 83.397 us; speedup vs baseline: 1.0481x; 1.0481x over previous
//
#include <hip/hip_runtime.h>
#include <hip/hip_bf16.h>

#define F_DIM 512
#define NT 512
#define DEPTH 5
#define NCOL (NT * DEPTH)   // 2560
#define BATCH 2048

typedef __attribute__((ext_vector_type(8))) short bf16x8;
typedef __attribute__((ext_vector_type(4))) float f32x4;

__device__ __forceinline__ void gl2lds16(const void* g, void* l) {
    __builtin_amdgcn_global_load_lds((const __attribute__((address_space(1))) void*)g,
                                     (__attribute__((address_space(3))) void*)l,
                                     16, 0, 0);
}

// ---------------------------------------------------------------------------
// Kernel 1: prep. Softmax blocks FIRST (0..159 — they head the serial
// dependency chain; 160 CUs instead of 80), cast blocks behind (160..1183).
// 256 threads/block everywhere. Softmax reduction order: 16 groups x 32
// sequential rows per column — identical partial-sum tree to all prior
// rounds => bit-identical Wt.
// ---------------------------------------------------------------------------
__global__ __launch_bounds__(256) void prep(const float* __restrict__ x,
                                            const float* __restrict__ fa,
                                            __hip_bfloat16* __restrict__ Xb,
                                            __hip_bfloat16* __restrict__ Wt) {
    if (blockIdx.x >= 160) {
        const size_t i = (size_t)(blockIdx.x - 160) * 256 + threadIdx.x;
        const float4 v = ((const float4*)x)[i];
        union { ushort4 u; __hip_bfloat16 h[4]; } pk;
        pk.h[0] = __float2bfloat16(v.x);
        pk.h[1] = __float2bfloat16(v.y);
        pk.h[2] = __float2bfloat16(v.z);
        pk.h[3] = __float2bfloat16(v.w);
        ((ushort4*)Xb)[i] = pk.u;
        return;
    }
    const int l = threadIdx.x & 15;
    const int g = threadIdx.x >> 4;          // 0..15
    const int col = blockIdx.x * 16 + l;
    const int f0 = g * 32;
    __shared__ float red[16][16];

    float e[32];
    float s = 0.f;
#pragma unroll
    for (int i = 0; i < 32; ++i) {
        e[i] = __expf(fa[(size_t)(f0 + i) * NCOL + col]);
        s += e[i];
    }
    red[g][l] = s;
    __syncthreads();

    float S = 0.f;
#pragma unroll
    for (int gg = 0; gg < 16; ++gg) S += red[gg][l];
    const float inv = 1.0f / S;

    __hip_bfloat16* dst = Wt + (size_t)col * F_DIM + f0;
#pragma unroll
    for (int i = 0; i < 32; i += 8) {
        union { uint4 u; __hip_bfloat16 h[8]; } pk;
#pragma unroll
        for (int jj = 0; jj < 8; ++jj)
            pk.h[jj] = __float2bfloat16(e[i + jj] * inv);
        *(uint4*)(dst + i) = pk.u;
    }
}

// ---------------------------------------------------------------------------
// Kernel 2: fused GEMM + tree routing — R1-exact structure (best measured).
// gl2lds width-16 staging for BOTH A and B (m151: beats reg-staging here),
// 2-phase LDS double-buffer with counted vmcnt(7): tile kt's 7 loads have
// had a full compute phase + barrier to land; tile kt+1's stay in flight
// across the barrier. LDS 2x28KB = 56KB -> 2 blocks/CU.
// ---------------------------------------------------------------------------
__global__ __launch_bounds__(256, 2) void gemm_tree(const __hip_bfloat16* __restrict__ A,
                                                    const __hip_bfloat16* __restrict__ Bt,
                                                    const float* __restrict__ th,
                                                    const float* __restrict__ lt,
                                                    const float* __restrict__ resp,
                                                    float* __restrict__ out) {
    __shared__ __align__(16) char smem[57344];   // 2 x (As 8KB + Bs 20KB); E slab reuses buf0

    const int tid = threadIdx.x;
    const int w = tid >> 6;
    const int l = tid & 63;
    const int m0 = blockIdx.y * 64;       // batch-row base
    const int n0c = blockIdx.x * 160;     // fv-column base
    const int n0t = blockIdx.x * 32;      // tree base
    const int wm = (w & 1) * 32;
    const int wn = (w >> 1) * 80;

    f32x4 acc[2][5] = {};

    const int srow = l >> 3;              // row within 8-row staging group
    const int schunk = (l & 7) ^ srow;    // xor-swizzled source chunk

    auto stage = [&](int kt, int buf) {
        const int k0 = kt * 64;
        char* base = smem + buf * 28672;
#pragma unroll
        for (int q = 0; q < 2; ++q) {     // As: 8 groups of 8 rows
            const int g = q * 4 + w;
            gl2lds16(A + ((size_t)(m0 + g * 8 + srow) * F_DIM + k0 + schunk * 8),
                     base + g * 8 * 64 * 2);
        }
#pragma unroll
        for (int q = 0; q < 5; ++q) {     // Bs: 20 groups of 8 rows
            const int g = q * 4 + w;
            gl2lds16(Bt + ((size_t)(n0c + g * 8 + srow) * F_DIM + k0 + schunk * 8),
                     base + 8192 + g * 8 * 64 * 2);
        }
    };

    stage(0, 0);
#pragma unroll
    for (int kt = 0; kt < 8; ++kt) {
        const int cur = kt & 1;
        __builtin_amdgcn_sched_barrier(0);
        if (kt < 7) {
            stage(kt + 1, cur ^ 1);       // prefetch next tile into other buffer
            asm volatile("s_waitcnt vmcnt(7)" ::: "memory");   // tile kt landed; kt+1 in flight
        } else {
            asm volatile("s_waitcnt vmcnt(0)" ::: "memory");
        }
        __builtin_amdgcn_s_barrier();
        __builtin_amdgcn_sched_barrier(0);

        const __hip_bfloat16* As = (const __hip_bfloat16*)(smem + cur * 28672);
        const __hip_bfloat16* Bs = As + 4096;   // +8192 bytes
#pragma unroll
        for (int ks = 0; ks < 2; ++ks) {
            const int cb = ks * 4 + (l >> 4);
            bf16x8 af[2], bfr[5];
#pragma unroll
            for (int im = 0; im < 2; ++im) {
                const int r = wm + im * 16 + (l & 15);
                af[im] = *(const bf16x8*)(As + r * 64 + ((cb ^ (r & 7)) * 8));
            }
#pragma unroll
            for (int in = 0; in < 5; ++in) {
                const int r = wn + in * 16 + (l & 15);
                bfr[in] = *(const bf16x8*)(Bs + r * 64 + ((cb ^ (r & 7)) * 8));
            }
#pragma unroll
            for (int im = 0; im < 2; ++im)
#pragma unroll
                for (int in = 0; in < 5; ++in)
                    acc[im][in] = __builtin_amdgcn_mfma_f32_16x16x32_bf16(
                        af[im], bfr[in], acc[im][in], 0, 0, 0);
        }
        __builtin_amdgcn_sched_barrier(0);
        __builtin_amdgcn_s_barrier();
    }
    __builtin_amdgcn_sched_barrier(0);

    // ---- tree epilogue ----
    float* E = (float*)smem;              // [32][161], reuses buf0 (last compute read buf1)
    const int tree = tid & 31;            // local tree 0..31
    const int rg = tid >> 5;              // row-group 0..7 (4 slab rows each)
    const int gt = n0t + tree;

    float al[DEPTH], be[DEPTH];
#pragma unroll
    for (int j = 0; j < DEPTH; ++j) {
        const float a = 0.5f * __expf(-lt[gt * DEPTH + j]);
        al[j] = a;
        be[j] = 0.5f - th[gt * DEPTH + j] * a;
    }
    float rs[32];
#pragma unroll
    for (int i = 0; i < 32; ++i) rs[i] = resp[gt * 32 + i];

    const int PAD = 161;
#pragma unroll
    for (int im = 0; im < 2; ++im) {
#pragma unroll
        for (int in = 0; in < 5; ++in) {
            const int scol = wn + in * 16 + (l & 15);
#pragma unroll
            for (int r = 0; r < 4; ++r) {
                const int sr = (w & 1) * 16 + (l >> 4) * 4 + r;
                E[sr * PAD + scol] = acc[im][in][r];
            }
        }
        __syncthreads();

#pragma unroll
        for (int rr = 0; rr < 4; ++rr) {
            const int s = rg * 4 + rr;                       // slab row 0..31
            const int gb = m0 + ((s < 16) ? (im * 16 + s) : (32 + im * 16 + (s - 16)));
            const float* f = E + s * PAD + tree * 5;
            float c1[DEPTH];
#pragma unroll
            for (int j = 0; j < DEPTH; ++j) {
                const float v = fmaf(al[j], f[j], be[j]);
                c1[j] = fminf(fmaxf(v, 0.f), 1.f);
            }
            float s16[16], s8[8], s4[4], s2[2];
#pragma unroll
            for (int m = 0; m < 16; ++m) s16[m] = fmaf(c1[0], rs[2*m+1] - rs[2*m], rs[2*m]);
#pragma unroll
            for (int m = 0; m < 8; ++m)  s8[m]  = fmaf(c1[1], s16[2*m+1] - s16[2*m], s16[2*m]);
#pragma unroll
            for (int m = 0; m < 4; ++m)  s4[m]  = fmaf(c1[2], s8[2*m+1] - s8[2*m], s8[2*m]);
#pragma unroll
            for (int m = 0; m < 2; ++m)  s2[m]  = fmaf(c1[3], s4[2*m+1] - s4[2*m], s4[2*m]);
            out[(size_t)gb * NT + gt] = fmaf(c1[4], s2[1] - s2[0], s2[0]);
        }
        __syncthreads();
    }
}

// ---------------------------------------------------------------------------
extern "C" void kernel_launch(void* const* d_in, const int* in_sizes, int n_in,
                              void* d_out, int out_size, void* d_ws, size_t ws_size,
                              hipStream_t stream) {
    const float* x    = (const float*)d_in[0];
    const float* fa   = (const float*)d_in[1];
    const float* th   = (const float*)d_in[2];
    const float* lt   = (const float*)d_in[3];
    const float* resp = (const float*)d_in[4];
    // d_in[5] = path_map: deterministic oblivious layout, hardcoded in epilogue.

    char* ws = (char*)d_ws;
    __hip_bfloat16* Wt = (__hip_bfloat16*)(ws);                 // 2560*512*2 = 2.62 MB
    __hip_bfloat16* Xb = (__hip_bfloat16*)(ws + (4u << 20));    // 2048*512*2 = 2.10 MB
    float* out = (float*)d_out;

    hipLaunchKernelGGL(prep, dim3(160 + 1024), dim3(256), 0, stream, x, fa, Xb, Wt);
    hipLaunchKernelGGL(gemm_tree, dim3(NCOL / 160, BATCH / 64), dim3(256), 0, stream,
                       Xb, Wt, th, lt, resp, out);
}

// Round 4
// 82.496 us; speedup vs baseline: 1.0596x; 1.0109x over previous
//
#include <hip/hip_runtime.h>
#include <hip/hip_bf16.h>

#define F_DIM 512
#define NT 512
#define DEPTH 5
#define NCOL (NT * DEPTH)   // 2560
#define BATCH 2048

typedef __attribute__((ext_vector_type(8))) short bf16x8;
typedef __attribute__((ext_vector_type(4))) float f32x4;

__device__ __forceinline__ void gl2lds16(const void* g, void* l) {
    __builtin_amdgcn_global_load_lds((const __attribute__((address_space(1))) void*)g,
                                     (__attribute__((address_space(3))) void*)l,
                                     16, 0, 0);
}

// ---------------------------------------------------------------------------
// Kernel 1: prep. Softmax blocks FIRST (0..79, they are the long pole),
// cast blocks behind (80..591). 512 threads/block.
// Softmax lane remap: 32 cols per block -> wave reads 2x128B segments/instr.
// Wt stores 16B wide. FP reduction order: 16 groups x 32 sequential rows
// => bit-identical Wt vs all prior rounds.
// This is the R1-measured-best prep geometry (81.78 us session best);
// R0/R3's 16-col variant measured ~83.5 twice.
// ---------------------------------------------------------------------------
__global__ __launch_bounds__(512) void prep(const float* __restrict__ x,
                                            const float* __restrict__ fa,
                                            __hip_bfloat16* __restrict__ Xb,
                                            __hip_bfloat16* __restrict__ Wt) {
    if (blockIdx.x >= 80) {
        const size_t i = (size_t)(blockIdx.x - 80) * 512 + threadIdx.x;
        const float4 v = ((const float4*)x)[i];
        union { ushort4 u; __hip_bfloat16 h[4]; } pk;
        pk.h[0] = __float2bfloat16(v.x);
        pk.h[1] = __float2bfloat16(v.y);
        pk.h[2] = __float2bfloat16(v.z);
        pk.h[3] = __float2bfloat16(v.w);
        ((ushort4*)Xb)[i] = pk.u;
        return;
    }
    const int l = threadIdx.x & 31;
    const int g = threadIdx.x >> 5;          // 0..15
    const int col = blockIdx.x * 32 + l;
    const int f0 = g * 32;
    __shared__ float red[16][32];

    float e[32];
    float s = 0.f;
#pragma unroll
    for (int i = 0; i < 32; ++i) {
        e[i] = __expf(fa[(size_t)(f0 + i) * NCOL + col]);
        s += e[i];
    }
    red[g][l] = s;
    __syncthreads();

    float S = 0.f;
#pragma unroll
    for (int gg = 0; gg < 16; ++gg) S += red[gg][l];
    const float inv = 1.0f / S;

    __hip_bfloat16* dst = Wt + (size_t)col * F_DIM + f0;
#pragma unroll
    for (int i = 0; i < 32; i += 8) {
        union { uint4 u; __hip_bfloat16 h[8]; } pk;
#pragma unroll
        for (int jj = 0; jj < 8; ++jj)
            pk.h[jj] = __float2bfloat16(e[i + jj] * inv);
        *(uint4*)(dst + i) = pk.u;
    }
}

// ---------------------------------------------------------------------------
// Kernel 2: fused GEMM + tree routing, v5 (R1-exact, best measured).
// gl2lds width-16 staging, 2-phase LDS double-buffer with counted vmcnt(7):
// tile kt's 7 loads have had a full compute phase + barrier to land; tile
// kt+1's stay in flight across the barrier (T4 discipline).
// LDS 2x28KB = 56KB -> 2 blocks/CU; epilogue E slab reuses buf0.
// ---------------------------------------------------------------------------
__global__ __launch_bounds__(256, 2) void gemm_tree(const __hip_bfloat16* __restrict__ A,
                                                    const __hip_bfloat16* __restrict__ Bt,
                                                    const float* __restrict__ th,
                                                    const float* __restrict__ lt,
                                                    const float* __restrict__ resp,
                                                    float* __restrict__ out) {
    __shared__ __align__(16) char smem[57344];   // 2 x (As 8KB + Bs 20KB); E slab reuses buf0

    const int tid = threadIdx.x;
    const int w = tid >> 6;
    const int l = tid & 63;
    const int m0 = blockIdx.y * 64;       // batch-row base
    const int n0c = blockIdx.x * 160;     // fv-column base
    const int n0t = blockIdx.x * 32;      // tree base
    const int wm = (w & 1) * 32;
    const int wn = (w >> 1) * 80;

    f32x4 acc[2][5] = {};

    const int srow = l >> 3;              // row within 8-row staging group
    const int schunk = (l & 7) ^ srow;    // xor-swizzled source chunk

    auto stage = [&](int kt, int buf) {
        const int k0 = kt * 64;
        char* base = smem + buf * 28672;
#pragma unroll
        for (int q = 0; q < 2; ++q) {     // As: 8 groups of 8 rows
            const int g = q * 4 + w;
            gl2lds16(A + ((size_t)(m0 + g * 8 + srow) * F_DIM + k0 + schunk * 8),
                     base + g * 8 * 64 * 2);
        }
#pragma unroll
        for (int q = 0; q < 5; ++q) {     // Bs: 20 groups of 8 rows
            const int g = q * 4 + w;
            gl2lds16(Bt + ((size_t)(n0c + g * 8 + srow) * F_DIM + k0 + schunk * 8),
                     base + 8192 + g * 8 * 64 * 2);
        }
    };

    stage(0, 0);
#pragma unroll
    for (int kt = 0; kt < 8; ++kt) {
        const int cur = kt & 1;
        __builtin_amdgcn_sched_barrier(0);
        if (kt < 7) {
            stage(kt + 1, cur ^ 1);       // prefetch next tile into other buffer
            asm volatile("s_waitcnt vmcnt(7)" ::: "memory");   // tile kt landed; kt+1 in flight
        } else {
            asm volatile("s_waitcnt vmcnt(0)" ::: "memory");
        }
        __builtin_amdgcn_s_barrier();
        __builtin_amdgcn_sched_barrier(0);

        const __hip_bfloat16* As = (const __hip_bfloat16*)(smem + cur * 28672);
        const __hip_bfloat16* Bs = As + 4096;   // +8192 bytes
#pragma unroll
        for (int ks = 0; ks < 2; ++ks) {
            const int cb = ks * 4 + (l >> 4);
            bf16x8 af[2], bfr[5];
#pragma unroll
            for (int im = 0; im < 2; ++im) {
                const int r = wm + im * 16 + (l & 15);
                af[im] = *(const bf16x8*)(As + r * 64 + ((cb ^ (r & 7)) * 8));
            }
#pragma unroll
            for (int in = 0; in < 5; ++in) {
                const int r = wn + in * 16 + (l & 15);
                bfr[in] = *(const bf16x8*)(Bs + r * 64 + ((cb ^ (r & 7)) * 8));
            }
#pragma unroll
            for (int im = 0; im < 2; ++im)
#pragma unroll
                for (int in = 0; in < 5; ++in)
                    acc[im][in] = __builtin_amdgcn_mfma_f32_16x16x32_bf16(
                        af[im], bfr[in], acc[im][in], 0, 0, 0);
        }
        __builtin_amdgcn_sched_barrier(0);
        __builtin_amdgcn_s_barrier();
    }
    __builtin_amdgcn_sched_barrier(0);

    // ---- tree epilogue ----
    float* E = (float*)smem;              // [32][161], reuses buf0 (last compute read buf1)
    const int tree = tid & 31;            // local tree 0..31
    const int rg = tid >> 5;              // row-group 0..7 (4 slab rows each)
    const int gt = n0t + tree;

    float al[DEPTH], be[DEPTH];
#pragma unroll
    for (int j = 0; j < DEPTH; ++j) {
        const float a = 0.5f * __expf(-lt[gt * DEPTH + j]);
        al[j] = a;
        be[j] = 0.5f - th[gt * DEPTH + j] * a;
    }
    float rs[32];
#pragma unroll
    for (int i = 0; i < 32; ++i) rs[i] = resp[gt * 32 + i];

    const int PAD = 161;
#pragma unroll
    for (int im = 0; im < 2; ++im) {
#pragma unroll
        for (int in = 0; in < 5; ++in) {
            const int scol = wn + in * 16 + (l & 15);
#pragma unroll
            for (int r = 0; r < 4; ++r) {
                const int sr = (w & 1) * 16 + (l >> 4) * 4 + r;
                E[sr * PAD + scol] = acc[im][in][r];
            }
        }
        __syncthreads();

#pragma unroll
        for (int rr = 0; rr < 4; ++rr) {
            const int s = rg * 4 + rr;                       // slab row 0..31
            const int gb = m0 + ((s < 16) ? (im * 16 + s) : (32 + im * 16 + (s - 16)));
            const float* f = E + s * PAD + tree * 5;
            float c1[DEPTH];
#pragma unroll
            for (int j = 0; j < DEPTH; ++j) {
                const float v = fmaf(al[j], f[j], be[j]);
                c1[j] = fminf(fmaxf(v, 0.f), 1.f);
            }
            float s16[16], s8[8], s4[4], s2[2];
#pragma unroll
            for (int m = 0; m < 16; ++m) s16[m] = fmaf(c1[0], rs[2*m+1] - rs[2*m], rs[2*m]);
#pragma unroll
            for (int m = 0; m < 8; ++m)  s8[m]  = fmaf(c1[1], s16[2*m+1] - s16[2*m], s16[2*m]);
#pragma unroll
            for (int m = 0; m < 4; ++m)  s4[m]  = fmaf(c1[2], s8[2*m+1] - s8[2*m], s8[2*m]);
#pragma unroll
            for (int m = 0; m < 2; ++m)  s2[m]  = fmaf(c1[3], s4[2*m+1] - s4[2*m], s4[2*m]);
            out[(size_t)gb * NT + gt] = fmaf(c1[4], s2[1] - s2[0], s2[0]);
        }
        __syncthreads();
    }
}

// ---------------------------------------------------------------------------
extern "C" void kernel_launch(void* const* d_in, const int* in_sizes, int n_in,
                              void* d_out, int out_size, void* d_ws, size_t ws_size,
                              hipStream_t stream) {
    const float* x    = (const float*)d_in[0];
    const float* fa   = (const float*)d_in[1];
    const float* th   = (const float*)d_in[2];
    const float* lt   = (const float*)d_in[3];
    const float* resp = (const float*)d_in[4];
    // d_in[5] = path_map: deterministic oblivious layout, hardcoded in epilogue.

    char* ws = (char*)d_ws;
    __hip_bfloat16* Wt = (__hip_bfloat16*)(ws);                 // 2560*512*2 = 2.62 MB
    __hip_bfloat16* Xb = (__hip_bfloat16*)(ws + (4u << 20));    // 2048*512*2 = 2.10 MB
    float* out = (float*)d_out;

    hipLaunchKernelGGL(prep, dim3(80 + 512), dim3(512), 0, stream, x, fa, Xb, Wt);
    hipLaunchKernelGGL(gemm_tree, dim3(NCOL / 160, BATCH / 64), dim3(256), 0, stream,
                       Xb, Wt, th, lt, resp, out);
}